// Round 1
// baseline (317.258 us; speedup 1.0000x reference)
//
#include <hip/hip_runtime.h>
#include <math.h>

// Problem: VectorQuantizer. inputs [32,64,64,64] fp32 NCHW (C=D=64), weight [512,64] fp32.
// N = 131072 queries, K = 512 codes, D = 64.
#define VQ_D 64
#define VQ_K 512
#define VQ_NQ 131072
#define VQ_TOTAL 8388608   // 32*64*64*64

// ---------------- prep: codebook norms (f64 + f32) ----------------
__global__ __launch_bounds__(512) void vq_prep(const float* __restrict__ w,
                                               float* __restrict__ wnormf,
                                               double* __restrict__ wnormd) {
    int k = threadIdx.x;  // one block of 512
    double s = 0.0;
#pragma unroll
    for (int d = 0; d < VQ_D; ++d) {
        double v = (double)w[k * VQ_D + d];
        s = fma(v, v, s);
    }
    wnormd[k] = s;
    wnormf[k] = (float)s;
}

// ---------------- main: argmin + gather + loss partials ----------------
__global__ __launch_bounds__(256) void vq_main(const float* __restrict__ in,
                                               const float* __restrict__ w,
                                               const float* __restrict__ wnormf,
                                               const double* __restrict__ wnormd,
                                               float* __restrict__ out,
                                               double* __restrict__ partials) {
    const int n  = blockIdx.x * 256 + threadIdx.x;   // query index
    const int b  = n >> 12;                          // / 4096
    const int hw = n & 4095;
    const float* xp = in + (b << 18) + hw;           // b*C*HW + hw, stride HW=4096 per d

    float x[VQ_D];
    float xnorm = 0.f;
#pragma unroll
    for (int d = 0; d < VQ_D; ++d) {
        x[d] = xp[d << 12];
        xnorm = fmaf(x[d], x[d], xnorm);
    }

    // Pass 1: fp32 distances dist_k = ||e_k||^2 - 2 x.e_k  (xnorm is a per-query constant).
    // Weight accesses are block-uniform -> compiler scalarizes to s_load; fmac reads SGPR.
    float best = 3.4e38f, second = 3.4e38f;
    int bidx = 0, sidx = 0;
    for (int k = 0; k < VQ_K; ++k) {
        const float* wk = w + k * VQ_D;
        float d0 = 0.f, d1 = 0.f, d2 = 0.f, d3 = 0.f;
#pragma unroll
        for (int d = 0; d < VQ_D; d += 4) {
            d0 = fmaf(x[d + 0], wk[d + 0], d0);
            d1 = fmaf(x[d + 1], wk[d + 1], d1);
            d2 = fmaf(x[d + 2], wk[d + 2], d2);
            d3 = fmaf(x[d + 3], wk[d + 3], d3);
        }
        float dot  = (d0 + d1) + (d2 + d3);
        float dist = fmaf(-2.f, dot, wnormf[k]);
        bool lt  = dist < best;
        bool lt2 = (!lt) && (dist < second);
        second = lt ? best : (lt2 ? dist : second);
        sidx   = lt ? bidx : (lt2 ? k    : sidx);
        best   = lt ? dist : best;
        bidx   = lt ? k    : bidx;
    }

    // Near-tie refinement: fp32 accumulation error bound ~3e-4 per dist; if the
    // best/second gap is under 4e-3, re-rank the two candidates in fp64 so our
    // argmin matches an exact-arithmetic (np float64) ordering.
    double chosen = (double)best;
    if (second - best < 4e-3f) {
        const float* wb = w + bidx * VQ_D;
        const float* ws_ = w + sidx * VQ_D;
        double dotb = 0.0, dots = 0.0;
#pragma unroll 8
        for (int d = 0; d < VQ_D; ++d) {
            dotb = fma((double)x[d], (double)wb[d], dotb);
            dots = fma((double)x[d], (double)ws_[d], dots);
        }
        double db = wnormd[bidx] - 2.0 * dotb;
        double ds = wnormd[sidx] - 2.0 * dots;
        bool swap = (ds < db) || (ds == db && sidx < bidx);  // argmin-first semantics
        if (swap) { bidx = sidx; chosen = ds; }
        else      { chosen = db; }
    }

    // Gather chosen codeword and scatter to NCHW output (coalesced across lanes per d).
    const float4* wrow = (const float4*)(w + bidx * VQ_D);
    float* op = out + (b << 18) + hw;
#pragma unroll
    for (int i = 0; i < 16; ++i) {
        float4 v = wrow[i];
        op[((4 * i + 0)) << 12] = v.x;
        op[((4 * i + 1)) << 12] = v.y;
        op[((4 * i + 2)) << 12] = v.z;
        op[((4 * i + 3)) << 12] = v.w;
    }

    // Loss contribution: ||x - e||^2 = xnorm + (wnorm - 2 dot) = xnorm + chosen.
    double lq = (double)xnorm + chosen;
#pragma unroll
    for (int off = 32; off > 0; off >>= 1)
        lq += __shfl_down(lq, off, 64);
    if ((threadIdx.x & 63) == 0)
        partials[blockIdx.x * 4 + (threadIdx.x >> 6)] = lq;
}

// ---------------- finalize: deterministic reduce of 2048 partials ----------------
__global__ __launch_bounds__(256) void vq_finalize(const double* __restrict__ partials,
                                                   float* __restrict__ out_loss) {
    __shared__ double buf[256];
    double s = 0.0;
    for (int i = threadIdx.x; i < 2048; i += 256) s += partials[i];
    buf[threadIdx.x] = s;
    __syncthreads();
    if (threadIdx.x == 0) {
        double t = 0.0;
        for (int i = 0; i < 256; ++i) t += buf[i];
        out_loss[0] = (float)(t / (double)VQ_TOTAL);
    }
}

extern "C" void kernel_launch(void* const* d_in, const int* in_sizes, int n_in,
                              void* d_out, int out_size, void* d_ws, size_t ws_size,
                              hipStream_t stream) {
    const float* in = (const float*)d_in[0];   // [32,64,64,64] NCHW
    const float* w  = (const float*)d_in[1];   // [512,64]
    float* out = (float*)d_out;                // [8388608] quantized NCHW + [1] loss

    char* ws = (char*)d_ws;
    float*  wnormf   = (float*)(ws);           // 512 * 4  = 2048 B
    double* wnormd   = (double*)(ws + 2048);   // 512 * 8  = 4096 B
    double* partials = (double*)(ws + 6144);   // 2048 * 8 = 16384 B

    vq_prep<<<1, 512, 0, stream>>>(w, wnormf, wnormd);
    vq_main<<<VQ_NQ / 256, 256, 0, stream>>>(in, w, wnormf, wnormd, out, partials);
    vq_finalize<<<1, 256, 0, stream>>>(partials, out + VQ_TOTAL);
}

// Round 2
// 300.476 us; speedup vs baseline: 1.0559x; 1.0559x over previous
//
#include <hip/hip_runtime.h>
#include <math.h>

// VectorQuantizer: inputs [32,64,64,64] fp32 NCHW (C=D=64), weight [512,64] fp32.
// N = 131072 queries, K = 512 codes, D = 64. Compute-bound: 4.3e9 fp32 MACs
// (no fp32 MFMA on CDNA4 -> vector ALU, floor ~55 us at 157 TF).
#define VQ_D 64
#define VQ_K 512
#define VQ_NQ 131072
#define VQ_TOTAL 8388608   // 32*64*64*64
#define QPB 128            // queries per block (2 threads each -> 256 threads)
#define KHALF 256          // codes per thread (K-split x2)
#define CHUNK 32           // codes per half per LDS chunk
#define NCHUNK 8           // KHALF / CHUNK

__global__ __launch_bounds__(256, 4) void vq_main(const float* __restrict__ in,
                                                  const float* __restrict__ w,
                                                  float* __restrict__ out) {
    __shared__ float lds_w[2 * CHUNK * VQ_D];   // 16 KB staged codes (both halves)
    __shared__ float lds_wn[VQ_K];              // 2 KB fp32 code norms
    __shared__ float lds_b[QPB], lds_s[QPB];    // half1 -> half0 result handoff
    __shared__ int   lds_bi[QPB], lds_si[QPB];

    const int tid = threadIdx.x;
    const int h   = tid >> 7;           // which K-half this thread scans
    const int qi  = tid & (QPB - 1);    // query within block
    const int n   = blockIdx.x * QPB + qi;
    const int b   = n >> 12;            // batch
    const int hw  = n & 4095;
    const float* xp = in + (b << 18) + hw;      // NCHW: stride 4096 per channel

    // ---- per-block codebook norms (fp32), strided rows are L2-hot ----
    for (int k = tid; k < VQ_K; k += 256) {
        const float4* wr = (const float4*)(w + k * VQ_D);
        float s0 = 0.f, s1 = 0.f, s2 = 0.f, s3 = 0.f;
#pragma unroll
        for (int i = 0; i < 16; ++i) {
            float4 v = wr[i];
            s0 = fmaf(v.x, v.x, s0); s1 = fmaf(v.y, v.y, s1);
            s2 = fmaf(v.z, v.z, s2); s3 = fmaf(v.w, v.w, s3);
        }
        lds_wn[k] = (s0 + s1) + (s2 + s3);
    }

    // ---- load query vector (coalesced per channel across lanes) ----
    float x[VQ_D];
    float xnorm = 0.f;
#pragma unroll
    for (int d = 0; d < VQ_D; ++d) {
        x[d] = xp[d << 12];
        xnorm = fmaf(x[d], x[d], xnorm);
    }

    float best = 3.4e38f, second = 3.4e38f;
    int bidx = 0, sidx = 0;

    const float4* w4  = (const float4*)w;   // 8192 float4 total
    float4* lds4 = (float4*)lds_w;

    for (int c = 0; c < NCHUNK; ++c) {
        __syncthreads();   // previous chunk fully consumed (and wnorm ready at c=0)
        // stage chunk c: half0 codes [c*32, c*32+32), half1 codes [256+c*32, ...)
        lds4[tid]       = w4[c * 512 + tid];
        lds4[tid + 256] = w4[c * 512 + tid + 256];
        lds4[tid + 512] = w4[4096 + c * 512 + tid];
        lds4[tid + 768] = w4[4096 + c * 512 + tid + 256];
        __syncthreads();

        const float* wl = lds_w + h * (CHUNK * VQ_D);
        const int kbase = h * KHALF + c * CHUNK;
#pragma unroll 2
        for (int j = 0; j < CHUNK; ++j) {
            const float* wk = wl + j * VQ_D;   // wave-uniform address -> LDS broadcast
            float d0 = 0.f, d1 = 0.f, d2 = 0.f, d3 = 0.f;
#pragma unroll
            for (int d = 0; d < VQ_D; d += 4) {
                d0 = fmaf(x[d + 0], wk[d + 0], d0);
                d1 = fmaf(x[d + 1], wk[d + 1], d1);
                d2 = fmaf(x[d + 2], wk[d + 2], d2);
                d3 = fmaf(x[d + 3], wk[d + 3], d3);
            }
            const int k = kbase + j;
            float dist = fmaf(-2.f, (d0 + d1) + (d2 + d3), lds_wn[k]);
            bool lt  = dist < best;
            bool lt2 = (!lt) && (dist < second);
            second = lt ? best : (lt2 ? dist : second);
            sidx   = lt ? bidx : (lt2 ? k    : sidx);
            best   = lt ? dist : best;
            bidx   = lt ? k    : bidx;
        }
    }

    // ---- merge the two K-halves (half0 indices are lower -> first-index ties) ----
    __syncthreads();
    if (h == 1) {
        lds_b[qi] = best;  lds_s[qi] = second;
        lds_bi[qi] = bidx; lds_si[qi] = sidx;
    }
    __syncthreads();
    if (h == 0) {
        const float b1 = lds_b[qi], s1v = lds_s[qi];
        const int   i1 = lds_bi[qi], si1 = lds_si[qi];
        float cb, cs; int cbi, csi;
        if (best <= b1) {                    // half0 wins ties (lower index)
            cb = best; cbi = bidx;
            if (b1 < second) { cs = b1;     csi = i1;   }
            else             { cs = second; csi = sidx; }
        } else {
            cb = b1; cbi = i1;
            if (best <= s1v) { cs = best; csi = bidx; }
            else             { cs = s1v;  csi = si1;  }
        }

        // ---- near-tie refinement in fp64 (norms computed inline) ----
        double chosen = (double)cb;
        if (cs - cb < 4e-3f) {
            const float* wb = w + cbi * VQ_D;
            const float* wsp = w + csi * VQ_D;
            double nb = 0.0, dotb = 0.0, ns = 0.0, dots = 0.0;
#pragma unroll 8
            for (int d = 0; d < VQ_D; ++d) {
                double xv = (double)x[d];
                double wbv = (double)wb[d], wsv = (double)wsp[d];
                nb = fma(wbv, wbv, nb);   dotb = fma(xv, wbv, dotb);
                ns = fma(wsv, wsv, ns);   dots = fma(xv, wsv, dots);
            }
            double db = nb - 2.0 * dotb;
            double ds = ns - 2.0 * dots;
            if (ds < db || (ds == db && csi < cbi)) { cbi = csi; chosen = ds; }
            else                                    { chosen = db; }
        }

        // ---- gather chosen code, scatter to NCHW (coalesced across 128 lanes/d) ----
        const float4* wrow = (const float4*)(w + cbi * VQ_D);
        float* op = out + (b << 18) + hw;
#pragma unroll
        for (int i = 0; i < 16; ++i) {
            float4 v = wrow[i];
            op[(4 * i + 0) << 12] = v.x;
            op[(4 * i + 1) << 12] = v.y;
            op[(4 * i + 2) << 12] = v.z;
            op[(4 * i + 3) << 12] = v.w;
        }

        // ---- loss: ||x-e||^2 = xnorm + (wnorm - 2 dot) ----
        double lq = (double)xnorm + chosen;
#pragma unroll
        for (int off = 32; off > 0; off >>= 1)
            lq += __shfl_down(lq, off, 64);
        if ((tid & 63) == 0)
            atomicAdd(out + VQ_TOTAL, (float)(lq * (1.0 / (double)VQ_TOTAL)));
    }
}

extern "C" void kernel_launch(void* const* d_in, const int* in_sizes, int n_in,
                              void* d_out, int out_size, void* d_ws, size_t ws_size,
                              hipStream_t stream) {
    const float* in = (const float*)d_in[0];   // [32,64,64,64] NCHW
    const float* w  = (const float*)d_in[1];   // [512,64]
    float* out = (float*)d_out;                // [8388608] quantized + [1] loss

    hipMemsetAsync(out + VQ_TOTAL, 0, sizeof(float), stream);  // zero loss accumulator
    vq_main<<<VQ_NQ / QPB, 256, 0, stream>>>(in, w, out);
}